// Round 8
// baseline (219.415 us; speedup 1.0000x reference)
//
#include <hip/hip_runtime.h>
#include <stdint.h>

#define GRAPHS 256
#define NPG    512
#define EPG    8192
#define NTOT   (GRAPHS*NPG)

typedef __attribute__((ext_vector_type(8))) short s16x8;
typedef __attribute__((ext_vector_type(4))) float f32x4;

__device__ __forceinline__ float bf2f(unsigned short u){
  union { unsigned int i; float f; } c; c.i = ((unsigned int)u)<<16; return c.f;
}
__device__ __forceinline__ unsigned short f2bf(float f){
  union { float f; unsigned int i; } c; c.f = f;
  unsigned int r = c.i + 0x7fffu + ((c.i>>16)&1u);   // RNE
  return (unsigned short)(r>>16);
}

// ---------- CSR build (once, shared by both layers) + out_isqrt -------------
__global__ __launch_bounds__(512) void k_csr(const int* __restrict__ src,
      const int* __restrict__ dst, const int* __restrict__ ntype,
      unsigned short* __restrict__ sorted_g, int* __restrict__ start_g,
      float* __restrict__ out_isqrt){
  __shared__ int hist[NPG], cursor[NPG], co[NPG], cs[NPG+1];
  __shared__ unsigned short ntype_sh[NPG];
  __shared__ unsigned short sorted[EPG];
  const int b=blockIdx.x, tid=threadIdx.x, eb=b*EPG, nb=b*NPG;
  for (int v=tid; v<NPG; v+=512){
    hist[v]=0; co[v]=0; ntype_sh[v]=(unsigned short)ntype[nb+v];
  }
  __syncthreads();
  for (int i=tid;i<EPG;i+=512){
    atomicAdd(&hist[dst[eb+i]&(NPG-1)],1);
    atomicAdd(&co[src[eb+i]&(NPG-1)],1);
  }
  __syncthreads();
  if (tid<64){
    int carry=0;
    #pragma unroll
    for (int c=0;c<8;c++){
      int sc=hist[64*c+tid];
      #pragma unroll
      for (int off=1;off<64;off<<=1){ int y=__shfl_up(sc,off); if (tid>=off) sc+=y; }
      cs[64*c+tid+1]=carry+sc;
      carry+=__shfl(sc,63);
    }
    if (tid==0) cs[0]=0;
  }
  __syncthreads();
  for (int v=tid;v<NPG;v+=512) cursor[v]=cs[v];
  __syncthreads();
  for (int i=tid;i<EPG;i+=512){
    const int s=src[eb+i]&(NPG-1), d=dst[eb+i]&(NPG-1);
    const int pos=atomicAdd(&cursor[d],1);
    sorted[pos]=(unsigned short)((ntype_sh[s]<<9)|s);
  }
  __syncthreads();
  for (int i=tid;i<EPG/2;i+=512)
    ((unsigned int*)(sorted_g+(size_t)eb))[i] = ((const unsigned int*)sorted)[i];
  for (int v=tid;v<=NPG;v+=512) start_g[b*(NPG+1)+v]=cs[v];
  for (int v=tid;v<NPG;v+=512){
    int a=co[v]; if(a<1)a=1;
    out_isqrt[nb+v]=rsqrtf((float)a);
  }
}

// ---------- prep: EW1T[c][t] = (emb@W1)^T bf16; W2T[n][k]=bf16(W2[k][n]) ----
__global__ __launch_bounds__(256) void k_prep(const float* __restrict__ emb,
      const float* __restrict__ W1, const float* __restrict__ W2,
      unsigned short* __restrict__ EW1T, unsigned short* __restrict__ W2T){
  const int gid = blockIdx.x*256 + threadIdx.x;   // 8192 + 16384 = 24576
  if (gid < 8192){
    const int t = gid>>7, c = gid&127;
    float acc=0.f;
    #pragma unroll 4
    for (int k=0;k<128;k++) acc += emb[t*128+k]*W1[k*128+c];
    EW1T[c*64+t]=f2bf(acc);
  } else {
    const int i = gid - 8192;
    const int n = i>>7, k = i&127;
    W2T[n*128+k] = f2bf(W2[k*128+n]);
  }
}

// ---------- layer-1: S-histogram + MFMA(S_hi/lo @ EW1) ----------------------
// block = (graph, half: 256 dst rows), 512 thr. Writes h1T[b*128+col][row] bf16
// h1T = relu(agg*in_isqrt + b1) * out_isqrt   (osc pre-folded for layer 2)
#define A1_LDS 73232
__global__ __launch_bounds__(512) void k_agg1(
      const unsigned short* __restrict__ sorted_g, const int* __restrict__ start_g,
      const unsigned short* __restrict__ EW1T, const float* __restrict__ out_isqrt,
      const float* __restrict__ b1, unsigned short* __restrict__ h1T){
  extern __shared__ char smem[];
  float* S      = (float*)(smem);               // [256][68]
  float* wsc    = (float*)(smem + 69632);       // [512]
  int*   sstart = (int*)  (smem + 71680);       // [257]
  float* bsh    = (float*)(smem + 72720);       // [128]
  const int bid=blockIdx.x, b=bid>>1, half=bid&1;
  const int v0=half*256, nb=b*NPG, tid=threadIdx.x;
  for (int i=tid; i<(256*68)/4; i+=512) ((f32x4*)S)[i]=(f32x4){0.f,0.f,0.f,0.f};
  for (int i=tid; i<NPG; i+=512) wsc[i]=out_isqrt[nb+i];
  for (int i=tid; i<257; i+=512) sstart[i]=start_g[b*(NPG+1)+v0+i];
  if (tid<128) bsh[tid]=b1[tid];
  __syncthreads();
  if (tid<256){
    const int beg=sstart[tid], end=sstart[tid+1];
    float* Sd = S + tid*68;
    const unsigned short* sg = sorted_g + (size_t)b*EPG;
    for (int i=beg;i<end;++i){
      const int ent = sg[i];
      Sd[ent>>9] += wsc[ent&511];
    }
  }
  __syncthreads();
  const int wave=tid>>6, lane=tid&63, l16=lane&15, quad=lane>>4;
  f32x4 acc[2][8];
  #pragma unroll
  for (int rt=0;rt<2;rt++)
    #pragma unroll
    for (int nt=0;nt<8;nt++) acc[rt][nt]=(f32x4){0.f,0.f,0.f,0.f};
  #pragma unroll
  for (int ks=0; ks<4; ++ks){                   // ks 0,1 = hi; 2,3 = lo
    const int kc = (ks&1)*32 + quad*8;
    s16x8 a[2];
    #pragma unroll
    for (int rt=0;rt<2;rt++){
      const int m = (wave*2+rt)*16 + l16;
      const float* sp = &S[m*68 + kc];
      f32x4 va = *(const f32x4*)sp;
      f32x4 vb = *(const f32x4*)(sp+4);
      union { s16x8 v; unsigned short u[8]; } pk;
      #pragma unroll
      for (int j=0;j<8;j++){
        const float f = (j<4)? va[j] : vb[j-4];
        const unsigned short hi = f2bf(f);
        pk.u[j] = (ks<2) ? hi : f2bf(f - bf2f(hi));
      }
      a[rt]=pk.v;
    }
    s16x8 bf[8];
    #pragma unroll
    for (int nt=0;nt<8;nt++)
      bf[nt]=__builtin_bit_cast(s16x8,
          *(const uint4*)(EW1T + (size_t)(nt*16+l16)*64 + kc));
    #pragma unroll
    for (int rt=0;rt<2;rt++)
      #pragma unroll
      for (int nt=0;nt<8;nt++)
        acc[rt][nt]=__builtin_amdgcn_mfma_f32_16x16x32_bf16(a[rt],bf[nt],acc[rt][nt],0,0,0);
  }
  #pragma unroll
  for (int rt=0;rt<2;rt++){
    const int mloc = (wave*2+rt)*16 + quad*4;
    float isq[4], os[4];
    #pragma unroll
    for (int r=0;r<4;r++){
      int d = sstart[mloc+r+1]-sstart[mloc+r]; if (d<1) d=1;
      isq[r]=rsqrtf((float)d);
      os[r]=wsc[v0+mloc+r];
    }
    #pragma unroll
    for (int nt=0;nt<8;nt++){
      const int col = nt*16+l16;
      const float bb = bsh[col];
      ushort4 st;
      float v;
      v = fmaxf(acc[rt][nt][0]*isq[0]+bb,0.f)*os[0]; st.x=f2bf(v);
      v = fmaxf(acc[rt][nt][1]*isq[1]+bb,0.f)*os[1]; st.y=f2bf(v);
      v = fmaxf(acc[rt][nt][2]*isq[2]+bb,0.f)*os[2]; st.z=f2bf(v);
      v = fmaxf(acc[rt][nt][3]*isq[3]+bb,0.f)*os[3]; st.w=f2bf(v);
      *(ushort4*)(h1T + ((size_t)(b*128+col))*512 + v0 + mloc) = st;
    }
  }
}

// ---------- layer-2 FUSED: (A-counts @ h1T)*isq -> Mt(LDS) @ W2T + b2, relu,
//            per-graph-tile column sums -> partial[(b*4+dt)*128 + col]
// LDS: A u8[128][520] (stage1) aliased by Mt bf16[128][136] + red[8][128] (stage2)
#define A2G_LDS 67600
__global__ __launch_bounds__(512) void k_agg2g(
      const unsigned short* __restrict__ sorted_g, const int* __restrict__ start_g,
      const unsigned short* __restrict__ h1T, const unsigned short* __restrict__ W2T,
      const float* __restrict__ b2, float* __restrict__ partial){
  extern __shared__ char smem[];
  unsigned char* A   = (unsigned char*)smem;        // [128][520] stage 1
  unsigned int*  A32 = (unsigned int*)smem;
  unsigned short* Mt = (unsigned short*)smem;       // [128][136] stage 2 (alias)
  float* red  = (float*)(smem + 34816);             // [8][128]   stage 2 (alias)
  int*   sstart = (int*)(smem + 66560);             // [129]
  float* bsh  = (float*)(smem + 67088);             // [128]
  const int bid=blockIdx.x;
  const int b  = ((bid>>5)<<3) | (bid&7);           // graph (XCD swizzle)
  const int dt = (bid>>3)&3;                        // dst tile
  const int v0=dt*128, tid=threadIdx.x;
  for (int i=tid; i<66560/16; i+=512) ((uint4*)smem)[i]=(uint4){0u,0u,0u,0u};
  for (int i=tid; i<129; i+=512) sstart[i]=start_g[b*(NPG+1)+v0+i];
  if (tid<128) bsh[tid]=b2[tid];
  __syncthreads();
  {                                                 // parallel count scatter
    const int d = tid>>2, q = tid&3;
    const int beg=sstart[d], end=sstart[d+1], len=end-beg;
    const int qb = beg + ((len*q)>>2), qe = beg + ((len*(q+1))>>2);
    const unsigned short* sg = sorted_g + (size_t)b*EPG;
    const int rowbase = d*130;
    for (int i=qb;i<qe;++i){
      const int s = sg[i]&511;
      atomicAdd(&A32[rowbase + (s>>2)], 1u<<((s&3)*8));
    }
  }
  __syncthreads();
  const int wave=tid>>6, lane=tid&63, l16=lane&15, quad=lane>>4;
  const int mg=wave>>1, ng=wave&1;                  // 2 Mtiles x 4 Ntiles / wave
  f32x4 acc[2][4];
  #pragma unroll
  for (int rt=0;rt<2;rt++)
    #pragma unroll
    for (int ct=0;ct<4;ct++) acc[rt][ct]=(f32x4){0.f,0.f,0.f,0.f};
  for (int ks=0; ks<16; ++ks){
    const int k = ks*32 + quad*8;
    s16x8 a[2], bf[4];
    #pragma unroll
    for (int rt=0;rt<2;rt++){
      const int m = (mg*2+rt)*16 + l16;
      const unsigned char* Ar = A + m*520 + k;
      const unsigned int w0 = *(const unsigned int*)(Ar);
      const unsigned int w1 = *(const unsigned int*)(Ar+4);
      union { s16x8 v; unsigned short u[8]; } pk;
      #pragma unroll
      for (int j=0;j<4;j++){
        const float f0 = (float)((w0>>(8*j))&0xffu);
        const float f1 = (float)((w1>>(8*j))&0xffu);
        pk.u[j]   = (unsigned short)(__builtin_bit_cast(unsigned int, f0)>>16);
        pk.u[j+4] = (unsigned short)(__builtin_bit_cast(unsigned int, f1)>>16);
      }
      a[rt]=pk.v;
    }
    #pragma unroll
    for (int ct=0;ct<4;ct++){
      const int n = (ng*4+ct)*16 + l16;
      bf[ct]=__builtin_bit_cast(s16x8,
          *(const uint4*)(h1T + ((size_t)(b*128+n))*512 + k));
    }
    #pragma unroll
    for (int rt=0;rt<2;rt++)
      #pragma unroll
      for (int ct=0;ct<4;ct++)
        acc[rt][ct]=__builtin_amdgcn_mfma_f32_16x16x32_bf16(a[rt],bf[ct],acc[rt][ct],0,0,0);
  }
  // epilogue stage 1: scale by in_isqrt, stash isq before barrier
  float isq[2][4];
  #pragma unroll
  for (int rt=0;rt<2;rt++){
    const int mloc=(mg*2+rt)*16 + quad*4;
    #pragma unroll
    for (int r=0;r<4;r++){
      int d=sstart[mloc+r+1]-sstart[mloc+r]; if (d<1) d=1;
      isq[rt][r]=rsqrtf((float)d);
    }
  }
  __syncthreads();                                  // all A reads done
  #pragma unroll
  for (int rt=0;rt<2;rt++){
    const int mloc=(mg*2+rt)*16 + quad*4;
    #pragma unroll
    for (int ct=0;ct<4;ct++){
      const int col=(ng*4+ct)*16+l16;
      #pragma unroll
      for (int r=0;r<4;r++)
        Mt[(mloc+r)*136 + col] = f2bf(acc[rt][ct][r]*isq[rt][r]);
    }
  }
  __syncthreads();
  // stage 2: Mt[128][128] @ W2T -> relu(+b2) -> column sums (graph mean partial)
  const int mt = wave;                              // one 16-row m-tile per wave
  f32x4 c2[8];
  #pragma unroll
  for (int ct=0;ct<8;ct++) c2[ct]=(f32x4){0.f,0.f,0.f,0.f};
  #pragma unroll
  for (int ks=0;ks<4;ks++){
    const int k = ks*32 + quad*8;
    s16x8 a = __builtin_bit_cast(s16x8, *(const uint4*)(Mt + (mt*16+l16)*136 + k));
    #pragma unroll
    for (int ct=0;ct<8;ct++){
      s16x8 bfr = __builtin_bit_cast(s16x8,
          *(const uint4*)(W2T + (size_t)(ct*16+l16)*128 + k));
      c2[ct]=__builtin_amdgcn_mfma_f32_16x16x32_bf16(a,bfr,c2[ct],0,0,0);
    }
  }
  float p[8];
  #pragma unroll
  for (int ct=0;ct<8;ct++){
    const float bb = bsh[ct*16+l16];
    float s = 0.f;
    #pragma unroll
    for (int r=0;r<4;r++) s += fmaxf(c2[ct][r]+bb,0.f);
    s += __shfl_xor(s,16);
    s += __shfl_xor(s,32);
    p[ct]=s;
  }
  if (quad==0){
    #pragma unroll
    for (int ct=0;ct<8;ct++) red[wave*128 + ct*16+l16]=p[ct];
  }
  __syncthreads();
  if (tid<128){
    float s=0.f;
    #pragma unroll
    for (int w=0;w<8;w++) s+=red[w*128+tid];
    partial[(size_t)(b*4+dt)*128 + tid]=s;
  }
}

// ---------- final: out[b][c] = sum_dt partial / 512 -------------------------
__global__ __launch_bounds__(256) void k_final(const float* __restrict__ partial,
      float* __restrict__ out){
  const int gid = blockIdx.x*256 + threadIdx.x;   // 32768
  const int b=gid>>7, c=gid&127;
  const float* p = partial + (size_t)(b*4)*128 + c;
  out[gid] = (p[0]+p[128]+p[256]+p[384])*(1.f/512.f);
}

extern "C" void kernel_launch(void* const* d_in, const int* in_sizes, int n_in,
                              void* d_out, int out_size, void* d_ws, size_t ws_size,
                              hipStream_t stream){
  const int* node_feat = (const int*)d_in[0];
  const int* src = (const int*)d_in[1];
  const int* dst = (const int*)d_in[2];
  const float* emb = (const float*)d_in[3];
  const float* W1  = (const float*)d_in[4];
  const float* b1  = (const float*)d_in[5];
  const float* W2  = (const float*)d_in[6];
  const float* b2  = (const float*)d_in[7];

  char* ws = (char*)d_ws;
  float* out_isqrt        = (float*)(ws);                          // 524288 B
  int* start_g            = (int*)(ws + 524288);                   // 525312 B
  unsigned short* sorted_g= (unsigned short*)(ws + 1049600);       // 4194304 B
  unsigned short* EW1T    = (unsigned short*)(ws + 5243904);       // 16384 B
  unsigned short* W2T     = (unsigned short*)(ws + 5260288);       // 32768 B
  unsigned short* h1T     = (unsigned short*)(ws + 5293056);       // 33554432 B
  float* partial          = (float*)(ws + 38847488);               // 524288 B

  (void)hipFuncSetAttribute(reinterpret_cast<const void*>(&k_agg1),
        hipFuncAttributeMaxDynamicSharedMemorySize, A1_LDS);
  (void)hipFuncSetAttribute(reinterpret_cast<const void*>(&k_agg2g),
        hipFuncAttributeMaxDynamicSharedMemorySize, A2G_LDS);

  k_csr<<<GRAPHS,512,0,stream>>>(src,dst,node_feat,sorted_g,start_g,out_isqrt);
  k_prep<<<96,256,0,stream>>>(emb,W1,W2,EW1T,W2T);
  k_agg1<<<GRAPHS*2,512,A1_LDS,stream>>>(sorted_g,start_g,EW1T,out_isqrt,b1,h1T);
  k_agg2g<<<GRAPHS*4,512,A2G_LDS,stream>>>(sorted_g,start_g,h1T,W2T,b2,partial);
  k_final<<<128,256,0,stream>>>(partial,(float*)d_out);
}